// Round 1
// 450.212 us; speedup vs baseline: 1.4656x; 1.4656x over previous
//
#include <hip/hip_runtime.h>
#include <hip/hip_bf16.h>

// Problem: B=32, C=256, CM=32, L=4096.  Inputs fp32, output fp32.
// V2: c-split x4 on both conv passes to fix grid-limited occupancy
// (was 256 blocks = 1 wave/SIMD, 11% occupancy, latency-bound).
// h kept as PRE-ReLU bf16 partials (4 chunks); k_combine sums+ReLUs them
// (exact: relu(sum of partials) == reference relu) and also runs the
// global branch in its bx==0 blocks.

#define NB 32
#define NC 256
#define NM 32
#define NL 4096
#define NL2 (NL / 2)       // float2 pairs per row
#define CSPLIT 4
#define CCH (NC / CSPLIT)  // 64 channels per chunk
#define BNEPS 1e-5f

typedef unsigned int u32;

// workspace layout (float offsets)
#define OFF_W1T   0                    // [NC*NM]  w1t[c*32+m] = lw1[m][c]*inv1[m]
#define OFF_B1F   (OFF_W1T + NC*NM)    // [NM]
#define OFF_W2F   (OFF_B1F + NM)       // [NC*NM]  w2f[c*32+m] = lw2[c][m]*inv2[c]
#define OFF_B2F   (OFF_W2F + NC*NM)    // [NC]
#define OFF_GW1T  (OFF_B2F + NC)       // [NC*NM]
#define OFF_GB1F  (OFF_GW1T + NC*NM)   // [NM]
#define OFF_GW2T  (OFF_GB1F + NM)      // [NM*NC]
#define OFF_GB2F  (OFF_GW2T + NM*NC)   // [NC]
#define OFF_AC    (OFF_GB2F + NC)      // [NB*NC]  b2f[c] + ga[b][c]
#define OFF_GMAX  (OFF_AC + NB*NC)     // [NB*NC]  encoded-float max (u32)
#define OFF_HP    (OFF_GMAX + NB*NC)   // u32 [CSPLIT][NB][NM][NL2] partials, 32 MiB
#define OFF_HC    (OFF_HP + CSPLIT*NB*NM*NL2)  // u32 [NB][NM][NL2] combined, 8 MiB

__device__ __forceinline__ unsigned f2u_mono(float f) {
    unsigned u = __float_as_uint(f);
    return (u & 0x80000000u) ? ~u : (u | 0x80000000u);
}
__device__ __forceinline__ float u2f_mono(unsigned u) {
    return (u & 0x80000000u) ? __uint_as_float(u & 0x7fffffffu)
                             : __uint_as_float(~u);
}
__device__ __forceinline__ void unpack2(u32 u, float& a, float& b) {
    a = __uint_as_float(u << 16);          // low half  = element 2k
    b = __uint_as_float(u & 0xffff0000u);  // high half = element 2k+1
}
__device__ __forceinline__ u32 pack2(float a, float b) {
    u32 ua = __bfloat16_as_ushort(__float2bfloat16(a));
    u32 ub = __bfloat16_as_ushort(__float2bfloat16(b));
    return ua | (ub << 16);
}

// ---------------- kernel A: fold BN into weights, init max cells -------------
__global__ __launch_bounds__(256) void k_fold(
    const float* __restrict__ lw1, const float* __restrict__ lb1,
    const float* __restrict__ lg1, const float* __restrict__ lbe1,
    const float* __restrict__ lm1, const float* __restrict__ lv1,
    const float* __restrict__ lw2, const float* __restrict__ lb2,
    const float* __restrict__ lg2, const float* __restrict__ lbe2,
    const float* __restrict__ lm2, const float* __restrict__ lv2,
    const float* __restrict__ gw1, const float* __restrict__ gb1,
    const float* __restrict__ gg1, const float* __restrict__ gbe1,
    const float* __restrict__ gm1, const float* __restrict__ gv1,
    const float* __restrict__ gw2, const float* __restrict__ gb2,
    const float* __restrict__ gg2, const float* __restrict__ gbe2,
    const float* __restrict__ gm2, const float* __restrict__ gv2,
    float* __restrict__ ws) {
    float* w1t  = ws + OFF_W1T;  float* b1f  = ws + OFF_B1F;
    float* w2f  = ws + OFF_W2F;  float* b2f  = ws + OFF_B2F;
    float* gw1t = ws + OFF_GW1T; float* gb1f = ws + OFF_GB1F;
    float* gw2t = ws + OFF_GW2T; float* gb2f = ws + OFF_GB2F;
    unsigned* gmaxU = (unsigned*)(ws + OFF_GMAX);

    int tid = blockIdx.x * blockDim.x + threadIdx.x;
    int nt  = gridDim.x * blockDim.x;
    for (int i = tid; i < NC * NM; i += nt) {
        int c = i >> 5, m = i & 31;
        float inv1 = lg1[m] * rsqrtf(lv1[m] + BNEPS);
        w1t[c * NM + m] = lw1[m * NC + c] * inv1;
        float gi1 = gg1[m] * rsqrtf(gv1[m] + BNEPS);
        gw1t[c * NM + m] = gw1[m * NC + c] * gi1;
        float inv2 = lg2[c] * rsqrtf(lv2[c] + BNEPS);
        w2f[c * NM + m] = lw2[c * NM + m] * inv2;
        float gi2 = gg2[c] * rsqrtf(gv2[c] + BNEPS);
        gw2t[m * NC + c] = gw2[c * NM + m] * gi2;
    }
    for (int i = tid; i < NM; i += nt) {
        float inv = lg1[i] * rsqrtf(lv1[i] + BNEPS);
        b1f[i] = lb1[i] * inv + lbe1[i] - lm1[i] * inv;
        float gi = gg1[i] * rsqrtf(gv1[i] + BNEPS);
        gb1f[i] = gb1[i] * gi + gbe1[i] - gm1[i] * gi;
    }
    for (int i = tid; i < NC; i += nt) {
        float inv = lg2[i] * rsqrtf(lv2[i] + BNEPS);
        b2f[i] = lb2[i] * inv + lbe2[i] - lm2[i] * inv;
        float gi = gg2[i] * rsqrtf(gv2[i] + BNEPS);
        gb2f[i] = gb2[i] * gi + gbe2[i] - gm2[i] * gi;
    }
    for (int i = tid; i < NB * NC; i += nt) gmaxU[i] = 0u;  // below all floats
}

// ---------------- kernel B: conv1x1 #1 partial (c-chunk) + channel max -------
// thread = one l-pair; block = 256 pairs of one (b, c-chunk); grid (8, 32, 4)
// 1024 blocks -> 4 blocks/CU -> 4 waves/SIMD.
__global__ __launch_bounds__(256, 4) void k_pass1(
    const float2* __restrict__ x2, const float2* __restrict__ y2,
    const float* __restrict__ w1t, const float* __restrict__ b1f,
    unsigned* __restrict__ gmaxU, u32* __restrict__ hp) {
    int b  = blockIdx.y;
    int cz = blockIdx.z;
    int p  = blockIdx.x * 256 + threadIdx.x;  // pair index in [0, 2048)
    const float2* xb = x2 + ((size_t)b * NC + (size_t)cz * CCH) * NL2 + p;
    const float2* yb = y2 + ((size_t)b * NC + (size_t)cz * CCH) * NL2 + p;

    float acc0[NM], acc1[NM];
    if (cz == 0) {
#pragma unroll
        for (int m = 0; m < NM; ++m) { acc0[m] = b1f[m]; acc1[m] = acc0[m]; }
    } else {
#pragma unroll
        for (int m = 0; m < NM; ++m) { acc0[m] = 0.f; acc1[m] = 0.f; }
    }

    __shared__ float wmax[4 * CCH];
    int wave = threadIdx.x >> 6;
    int lane = threadIdx.x & 63;
    const float* wbase = w1t + cz * CCH * NM;

#pragma unroll 4
    for (int c = 0; c < CCH; ++c) {
        float2 xv = xb[(size_t)c * NL2];
        float2 yv = yb[(size_t)c * NL2];
        float v0 = xv.x + yv.x, v1 = xv.y + yv.y;
        const float* wc = wbase + c * NM;  // wave-uniform -> scalar loads
#pragma unroll
        for (int m = 0; m < NM; ++m) {
            acc0[m] = fmaf(wc[m], v0, acc0[m]);
            acc1[m] = fmaf(wc[m], v1, acc1[m]);
        }
        float mv = fmaxf(v0, v1);
#pragma unroll
        for (int off = 32; off; off >>= 1) mv = fmaxf(mv, __shfl_down(mv, off));
        if (lane == 0) wmax[wave * CCH + c] = mv;
    }
    __syncthreads();
    if (threadIdx.x < CCH) {
        int c = threadIdx.x;
        float m0 = fmaxf(fmaxf(wmax[c], wmax[CCH + c]),
                         fmaxf(wmax[2 * CCH + c], wmax[3 * CCH + c]));
        atomicMax(&gmaxU[b * NC + cz * CCH + c], f2u_mono(m0));
    }
    // pre-ReLU bf16 partial for this c-chunk
    u32* hb = hp + (((size_t)cz * NB + b) * NM) * NL2 + p;
#pragma unroll
    for (int m = 0; m < NM; ++m)
        hb[(size_t)m * NL2] = pack2(acc0[m], acc1[m]);
}

// ---------------- kernel C: combine partials + ReLU; bx==0 does global branch
// grid (8, 32, 4): z splits m into groups of 8.
__global__ __launch_bounds__(256, 4) void k_combine(
    const u32* __restrict__ hp, u32* __restrict__ hc,
    const float* __restrict__ gw1t, const float* __restrict__ gb1f,
    const float* __restrict__ gw2t, const float* __restrict__ gb2f,
    const float* __restrict__ b2f, const unsigned* __restrict__ gmaxU,
    float* __restrict__ ac) {
    int b  = blockIdx.y;
    int mz = blockIdx.z;
    int p  = blockIdx.x * 256 + threadIdx.x;
#pragma unroll
    for (int mi = 0; mi < NM / 4; ++mi) {
        int m = mz * (NM / 4) + mi;
        size_t off = ((size_t)b * NM + m) * NL2 + p;
        float s0 = 0.f, s1 = 0.f;
#pragma unroll
        for (int cz = 0; cz < CSPLIT; ++cz) {
            float a, bv;
            unpack2(hp[(size_t)cz * NB * NM * NL2 + off], a, bv);
            s0 += a; s1 += bv;
        }
        hc[off] = pack2(fmaxf(s0, 0.f), fmaxf(s1, 0.f));
    }

    // global branch (maxpool -> FC -> ReLU -> FC), once per b
    if (blockIdx.x == 0 && mz == 0) {
        __shared__ float smax[NC];
        __shared__ float g1[NM];
        int t = threadIdx.x;
        smax[t] = u2f_mono(gmaxU[b * NC + t]);
        __syncthreads();
        if (t < NM) {
            float a = gb1f[t];
            for (int c = 0; c < NC; ++c) a = fmaf(gw1t[c * NM + t], smax[c], a);
            g1[t] = fmaxf(a, 0.f);
        }
        __syncthreads();
        float a = b2f[t] + gb2f[t];
#pragma unroll
        for (int m = 0; m < NM; ++m) a = fmaf(gw2t[m * NC + t], g1[m], a);
        ac[b * NC + t] = a;  // = b2f[c] + ga[b][c]
    }
}

// ---------------- kernel D: conv1x1 #2 + sigmoid + blend -> fp32 -------------
// grid (8, 32, 4): z splits OUTPUT channels (independent), 4 waves/SIMD.
__global__ __launch_bounds__(256, 4) void k_pass2(
    const float2* __restrict__ x2, const float2* __restrict__ y2,
    const float* __restrict__ w2f, const float* __restrict__ ac,
    const u32* __restrict__ hc, float2* __restrict__ out2) {
    __shared__ float acl[CCH];
    int b  = blockIdx.y;
    int oz = blockIdx.z;
    int p  = blockIdx.x * 256 + threadIdx.x;
    if (threadIdx.x < CCH)
        acl[threadIdx.x] = ac[b * NC + oz * CCH + threadIdx.x];

    const u32* hb = hc + ((size_t)b * NM) * NL2 + p;
    float h0[NM], h1[NM];
#pragma unroll
    for (int m = 0; m < NM; ++m) unpack2(hb[(size_t)m * NL2], h0[m], h1[m]);
    __syncthreads();

    const float2* xb = x2 + ((size_t)b * NC + (size_t)oz * CCH) * NL2 + p;
    const float2* yb = y2 + ((size_t)b * NC + (size_t)oz * CCH) * NL2 + p;
    float2* ob = out2 + ((size_t)b * NC + (size_t)oz * CCH) * NL2 + p;
    const float* wbase = w2f + oz * CCH * NM;

#pragma unroll 4
    for (int c = 0; c < CCH; ++c) {
        const float* wc = wbase + c * NM;  // wave-uniform -> scalar loads
        float z0 = acl[c], z1 = z0;
#pragma unroll
        for (int m = 0; m < NM; ++m) {
            z0 = fmaf(wc[m], h0[m], z0);
            z1 = fmaf(wc[m], h1[m], z1);
        }
        float att0 = 1.f / (1.f + __expf(-z0));
        float att1 = 1.f / (1.f + __expf(-z1));
        float2 xv = xb[(size_t)c * NL2];
        float2 yv = yb[(size_t)c * NL2];
        float t0 = yv.x + att0 * (xv.x - yv.x);
        float t1 = yv.y + att1 * (xv.y - yv.y);
        float2 o; o.x = t0 + t0; o.y = t1 + t1;  // 2*(y + att*(x-y))
        ob[(size_t)c * NL2] = o;
    }
}

extern "C" void kernel_launch(void* const* d_in, const int* in_sizes, int n_in,
                              void* d_out, int out_size, void* d_ws,
                              size_t ws_size, hipStream_t stream) {
    (void)in_sizes; (void)n_in; (void)out_size; (void)ws_size;
    const float2* x2 = (const float2*)d_in[0];
    const float2* y2 = (const float2*)d_in[1];
    float* ws = (float*)d_ws;
    float2* out2 = (float2*)d_out;

    float* w1t  = ws + OFF_W1T;  float* b1f  = ws + OFF_B1F;
    float* w2f  = ws + OFF_W2F;  float* b2f  = ws + OFF_B2F;
    float* gw1t = ws + OFF_GW1T; float* gb1f = ws + OFF_GB1F;
    float* gw2t = ws + OFF_GW2T; float* gb2f = ws + OFF_GB2F;
    float* ac   = ws + OFF_AC;
    unsigned* gmaxU = (unsigned*)(ws + OFF_GMAX);
    u32* hp = (u32*)(ws + OFF_HP);
    u32* hc = (u32*)(ws + OFF_HC);

    k_fold<<<64, 256, 0, stream>>>(
        (const float*)d_in[2],  (const float*)d_in[3],  (const float*)d_in[4],
        (const float*)d_in[5],  (const float*)d_in[6],  (const float*)d_in[7],
        (const float*)d_in[8],  (const float*)d_in[9],  (const float*)d_in[10],
        (const float*)d_in[11], (const float*)d_in[12], (const float*)d_in[13],
        (const float*)d_in[14], (const float*)d_in[15], (const float*)d_in[16],
        (const float*)d_in[17], (const float*)d_in[18], (const float*)d_in[19],
        (const float*)d_in[20], (const float*)d_in[21], (const float*)d_in[22],
        (const float*)d_in[23], (const float*)d_in[24], (const float*)d_in[25],
        ws);
    k_pass1<<<dim3(NL2 / 256, NB, CSPLIT), 256, 0, stream>>>(
        x2, y2, w1t, b1f, gmaxU, hp);
    k_combine<<<dim3(NL2 / 256, NB, 4), 256, 0, stream>>>(
        hp, hc, gw1t, gb1f, gw2t, gb2f, b2f, gmaxU, ac);
    k_pass2<<<dim3(NL2 / 256, NB, CSPLIT), 256, 0, stream>>>(
        x2, y2, w2f, ac, hc, out2);
}